// Round 10
// baseline (653.340 us; speedup 1.0000x reference)
//
#include <hip/hip_runtime.h>
#include <stdint.h>

// Axial attention (H axis), N=8 H=128 W=128 C=512, GROUPS=8, gp=64.
// Pipeline: wconv -> xconv(bf16+permute) -> QKV GEMM -> FUSED attn+outproj.
// R10 fix vs R9: B1 waits VMC(0) not VMC(2) — the counted wait assumed the 2 V reg-loads
// were the newest queue entries, but LLVM may reorder global reg-loads vs global_load_lds
// (no visible dependency) leaving Q/K staging in flight across the barrier -> stale LDS.
// VMC(0) is order-immune. sched_barrier(0) pins the issue cluster.

typedef __attribute__((ext_vector_type(4))) float f32x4;
typedef __attribute__((ext_vector_type(8))) short bf16x8;
typedef unsigned short u16;
typedef unsigned int u32;

#define CBAR() asm volatile("" ::: "memory")
#define SBAR() do { CBAR(); __builtin_amdgcn_s_barrier(); CBAR(); } while(0)
#define LGKM0() do { asm volatile("s_waitcnt lgkmcnt(0)" ::: "memory"); __builtin_amdgcn_sched_barrier(0); } while(0)
#define LGKMW() asm volatile("s_waitcnt lgkmcnt(0)" ::: "memory")
#define VMC(n) asm volatile("s_waitcnt vmcnt(" #n ")" ::: "memory")

static __device__ __forceinline__ u16 f2bf(float f){
    union { float f; u32 u; } v; v.f = f;
    u32 r = v.u + 0x7fffu + ((v.u >> 16) & 1u);   // RNE
    return (u16)(r >> 16);
}

static __device__ __forceinline__ void gload16(const void* g, void* l){
    __builtin_amdgcn_global_load_lds((const __attribute__((address_space(1))) void*)g,
                                     (__attribute__((address_space(3))) void*)l, 16, 0, 0);
}

// ---------------- weights fp32 -> bf16 ----------------
__global__ void k_wconv(const float* __restrict__ Wq, const float* __restrict__ Wk,
                        const float* __restrict__ Wv, const float* __restrict__ Wo,
                        u16* __restrict__ Wcat, u16* __restrict__ Wob){
    int e = (blockIdx.x * 256 + threadIdx.x) * 4;
    if (e < 1536*512) {
        int row = e >> 9, col = e & 511;
        const float* s = (row < 512) ? (Wq + row*512)
                        : (row < 1024 ? Wk + (row-512)*512 : Wv + (row-1024)*512);
        float4 v = *(const float4*)(s + col);
        ushort4 o = { f2bf(v.x), f2bf(v.y), f2bf(v.z), f2bf(v.w) };
        *(ushort4*)(Wcat + e) = o;
    } else {
        int e2 = e - 1536*512;
        float4 v = *(const float4*)(Wo + e2);
        ushort4 o = { f2bf(v.x), f2bf(v.y), f2bf(v.z), f2bf(v.w) };
        *(ushort4*)(Wob + e2) = o;
    }
}

// ---------------- x fp32 (N,H,W,C) -> xb bf16 [(n0+nl)*128+h][512] ----------------
__global__ void k_xconv(const float* __restrict__ x, u16* __restrict__ xb, int n0){
    int t = blockIdx.x * 256 + threadIdx.x;
    int ml = t >> 6;
    int c0 = (t & 63) << 3;
    int nl = ml >> 7, h = ml & 127;
    int n = n0 + nl, nb = n >> 7, w = n & 127;
    const float* src = x + (size_t)((nb*128 + h)*128 + w) * 512 + c0;
    float4 a = *(const float4*)(src);
    float4 b = *(const float4*)(src + 4);
    uint4 o;
    o.x = (u32)f2bf(a.x) | ((u32)f2bf(a.y) << 16);
    o.y = (u32)f2bf(a.z) | ((u32)f2bf(a.w) << 16);
    o.z = (u32)f2bf(b.x) | ((u32)f2bf(b.y) << 16);
    o.w = (u32)f2bf(b.z) | ((u32)f2bf(b.w) << 16);
    *(uint4*)(xb + (size_t)ml*512 + c0) = o;
}

// ---------------- 256x256 QKV GEMM (R7/R8 structure, frozen) ----------------
template<int NCOL>
__global__ __launch_bounds__(512, 2) void k_gemm4(const u16* __restrict__ A, const u16* __restrict__ B,
                                                  u16* __restrict__ Cout, int nrow, int planesz){
    extern __shared__ char smc[];
    const int tid = threadIdx.x;
    const int wid = tid >> 6, lane = tid & 63, lg = lane >> 4, li = lane & 15;
    const int wm = wid >> 2, wn = wid & 3;
    const int bid = blockIdx.x;
    const int xcd = bid & 7, l = bid >> 3;
    const int row_tile = xcd * (nrow >> 3) + l / NCOL;
    const int col_tile = l % NCOL;
    const int m0 = row_tile * 256, nn0 = col_tile * 256;

    const char* baseA[2]; const char* baseB[2]; int dstR[2];
    #pragma unroll
    for (int i = 0; i < 2; ++i) {
        int R = wid*32 + i*16;
        int r = R + (lane >> 2);
        int cq = (lane & 3) ^ ((r >> 1) & 3);
        baseA[i] = (const char*)(A + (size_t)(m0 + r)*512) + cq*16;
        baseB[i] = (const char*)(B + (size_t)(nn0 + r)*512) + cq*16;
        dstR[i] = R;
    }
    auto stageA = [&](int st){
        char* sl = smc + (st & 3)*32768;
        #pragma unroll
        for (int i = 0; i < 2; ++i) gload16(baseA[i] + st*64, sl + dstR[i]*64);
    };
    auto stageB = [&](int st){
        char* sl = smc + (st & 3)*32768 + 16384;
        #pragma unroll
        for (int i = 0; i < 2; ++i) gload16(baseB[i] + st*64, sl + dstR[i]*64);
    };

    f32x4 acc[8][4];
    #pragma unroll
    for (int i = 0; i < 8; ++i)
        #pragma unroll
        for (int j = 0; j < 4; ++j)
            acc[i][j] = f32x4{0.f, 0.f, 0.f, 0.f};

    stageA(0); stageB(0);
    stageA(1); stageB(1);
    stageA(2); stageB(2);
    VMC(8);
    SBAR();

    bf16x8 af[4], bfr[4];
    for (int t = 0; t < 16; ++t) {
        char* sl = smc + (t & 3)*32768;
        #pragma unroll
        for (int f = 0; f < 4; ++f) {
            int ra = wm*128 + f*16 + li;
            af[f] = *(const bf16x8*)(sl + ra*64 + (((lg ^ (ra >> 1)) & 3) << 4));
        }
        #pragma unroll
        for (int f = 0; f < 4; ++f) {
            int rb = wn*64 + f*16 + li;
            bfr[f] = *(const bf16x8*)(sl + 16384 + rb*64 + (((lg ^ (rb >> 1)) & 3) << 4));
        }
        if (t < 13) stageA(t + 3);
        SBAR(); LGKM0();
        __builtin_amdgcn_s_setprio(1);
        #pragma unroll
        for (int fi = 0; fi < 4; ++fi)
            #pragma unroll
            for (int fj = 0; fj < 4; ++fj)
                acc[fi][fj] = __builtin_amdgcn_mfma_f32_16x16x32_bf16(af[fi], bfr[fj], acc[fi][fj], 0, 0, 0);
        __builtin_amdgcn_s_setprio(0);
        SBAR();
        #pragma unroll
        for (int f = 0; f < 4; ++f) {
            int ra = wm*128 + (4 + f)*16 + li;
            af[f] = *(const bf16x8*)(sl + ra*64 + (((lg ^ (ra >> 1)) & 3) << 4));
        }
        if (t < 13) stageB(t + 3);
        SBAR(); LGKM0();
        __builtin_amdgcn_s_setprio(1);
        #pragma unroll
        for (int fi = 0; fi < 4; ++fi)
            #pragma unroll
            for (int fj = 0; fj < 4; ++fj)
                acc[4 + fi][fj] = __builtin_amdgcn_mfma_f32_16x16x32_bf16(af[fi], bfr[fj], acc[4 + fi][fj], 0, 0, 0);
        __builtin_amdgcn_s_setprio(0);
        if (t < 13)      { VMC(8); }
        else if (t == 13){ VMC(4); }
        else if (t == 14){ VMC(0); }
        SBAR();
    }

    u16* Cp = Cout + (size_t)(nn0 >> 9) * planesz;
    const int cb = (nn0 & 511) + wn*64;
    #pragma unroll
    for (int mf = 0; mf < 8; ++mf)
        #pragma unroll
        for (int nf = 0; nf < 4; ++nf)
            #pragma unroll
            for (int r = 0; r < 4; ++r) {
                int row = m0 + wm*128 + mf*16 + lg*4 + r;
                int col = cb + nf*16 + li;
                Cp[(size_t)row*512 + col] = f2bf(acc[mf][nf][r]);
            }
}

// ---------------- fused attention + outproj ----------------
// LDS (160KB): O region [0,128K) = 8 slots x 16KB; slot g: o(i,c)=g*16K + i*128
//   + ((c*2)^((i&7)<<4)) [i=0..127, c=0..63]. During group g, slot g holds Vt:
//   vt(c,j)=g*16K + c*256 + ((j*2)^((c&7)<<4)) — freed by PV before the O-write.
// Scratch [128K,160K): Q(16K)+K(16K); P overlays it after QK^T (8 waves x 4K);
//   outproj Bs overlays it per kc.
// Barriers/group: B1 (VMC(0): Q/K staged AND V regs landed — order-immune),
// B2 (Q/K reads done -> P overlay legal), B3 (LGKMW: P+Vt visible), B4 (P/Vt reads
// done -> O-write + next-group staging legal).
__global__ __launch_bounds__(512, 2) void k_fused(const u16* __restrict__ Qpl, const u16* __restrict__ Kpl,
                                                  const u16* __restrict__ Vpl, const u16* __restrict__ Wob,
                                                  const float* __restrict__ bias, float* __restrict__ out,
                                                  int n0, int cnd8){
    extern __shared__ char sm[];
    const int tid = threadIdx.x;
    const int wv = tid >> 6, lane = tid & 63, lg = lane >> 4, li = lane & 15;
    const int bid = blockIdx.x;
    const int nlL = (bid & 7)*cnd8 + (bid >> 3);
    const int n = n0 + nlL, nb = n >> 7, w = n & 127;

    char* const QB = sm + 131072;
    char* const KB = sm + 131072 + 16384;
    char* const PB = sm + 131072 + wv*4096;
    char* const SB = sm + 131072;

    const int vj = tid & 127, vch = tid >> 7;          // V loader role
    const size_t rowbase = (size_t)nlL * 128;

    auto issueQK = [&](int g){
        #pragma unroll
        for (int t = 0; t < 2; ++t) {
            int i = t*64 + (tid >> 3);
            int cq = (tid & 7) ^ (i & 7);
            gload16(Qpl + (rowbase + i)*512 + g*64 + cq*8, QB + t*8192 + tid*16);
            gload16(Kpl + (rowbase + i)*512 + g*64 + cq*8, KB + t*8192 + tid*16);
        }
    };

    uint4 va, vb;
    auto issueV = [&](int g){
        const u16* src = Vpl + (rowbase + vj)*512 + g*64 + vch*16;
        va = *(const uint4*)(src);
        vb = *(const uint4*)(src + 8);
    };

    // prologue: group 0 loads
    issueQK(0);
    issueV(0);
    __builtin_amdgcn_sched_barrier(0);

    for (int g = 0; g < 8; ++g) {
        char* OG = sm + g*16384;

        VMC(0);            // Q/K staged AND V regs landed (order-immune drain)
        SBAR();            // B1

        // ---- QK^T: S[16 rows/wave][128 j]
        f32x4 s8[8];
        #pragma unroll
        for (int tj = 0; tj < 8; ++tj) s8[tj] = f32x4{0.f,0.f,0.f,0.f};
        #pragma unroll
        for (int ks = 0; ks < 2; ++ks) {
            int i = wv*16 + li;
            bf16x8 qf = *(const bf16x8*)(QB + i*128 + ((ks*64 + lg*16) ^ ((li & 7) << 4)));
            #pragma unroll
            for (int tj = 0; tj < 8; ++tj) {
                int j = tj*16 + li;
                bf16x8 kf = *(const bf16x8*)(KB + j*128 + ((ks*64 + lg*16) ^ ((li & 7) << 4)));
                s8[tj] = __builtin_amdgcn_mfma_f32_16x16x32_bf16(qf, kf, s8[tj], 0, 0, 0);
            }
        }

        // ---- V scatter into slot g (Vt): disjoint from Q/K/P regions
        {
            u32 wd[8] = {va.x, va.y, va.z, va.w, vb.x, vb.y, vb.z, vb.w};
            #pragma unroll
            for (int cc = 0; cc < 16; ++cc) {
                int c = vch*16 + cc;
                u16 val = (cc & 1) ? (u16)(wd[cc >> 1] >> 16) : (u16)(wd[cc >> 1] & 0xffffu);
                *(u16*)(OG + c*256 + ((vj*2) ^ ((c & 7) << 4))) = val;
            }
        }

        SBAR();            // B2: all Q/K reads done -> P overlay legal

        // ---- softmax (scale 1/8) + P write (own wave's 4KB)
        #pragma unroll
        for (int r = 0; r < 4; ++r) {
            int ir = lg*4 + r;
            float mx = -1e30f;
            #pragma unroll
            for (int tj = 0; tj < 8; ++tj) mx = fmaxf(mx, s8[tj][r]);
            #pragma unroll
            for (int off = 1; off < 16; off <<= 1) mx = fmaxf(mx, __shfl_xor(mx, off, 64));
            float p[8]; float sum = 0.f;
            #pragma unroll
            for (int tj = 0; tj < 8; ++tj) { p[tj] = __expf((s8[tj][r] - mx)*0.125f); sum += p[tj]; }
            #pragma unroll
            for (int off = 1; off < 16; off <<= 1) sum += __shfl_xor(sum, off, 64);
            float inv = 1.0f / sum;
            #pragma unroll
            for (int tj = 0; tj < 8; ++tj) {
                int j = tj*16 + li;
                *(u16*)(PB + ir*256 + ((j*2) ^ ((ir & 7) << 4))) = f2bf(p[tj]*inv);
            }
        }

        LGKMW();
        SBAR();            // B3: P + Vt visible

        // ---- PV: O rows 16/wave x 64 c
        f32x4 o4[4];
        #pragma unroll
        for (int tc = 0; tc < 4; ++tc) o4[tc] = f32x4{0.f,0.f,0.f,0.f};
        #pragma unroll
        for (int ks = 0; ks < 4; ++ks) {
            bf16x8 pf = *(const bf16x8*)(PB + li*256 + ((ks*64 + lg*16) ^ ((li & 7) << 4)));
            #pragma unroll
            for (int tc = 0; tc < 4; ++tc) {
                int c = tc*16 + li;
                bf16x8 vf = *(const bf16x8*)(OG + c*256 + ((ks*64 + lg*16) ^ ((c & 7) << 4)));
                o4[tc] = __builtin_amdgcn_mfma_f32_16x16x32_bf16(pf, vf, o4[tc], 0, 0, 0);
            }
        }

        SBAR();            // B4: P/Vt reads done -> slot g + scratch reusable

        if (g < 7) {       // hide latency under O-write
            issueQK(g + 1);
            issueV(g + 1);
            __builtin_amdgcn_sched_barrier(0);
        }

        // ---- O_g -> slot g (overwrites Vt)
        #pragma unroll
        for (int tc = 0; tc < 4; ++tc)
            #pragma unroll
            for (int r = 0; r < 4; ++r) {
                int i = wv*16 + lg*4 + r;
                int c = tc*16 + li;
                *(u16*)(OG + i*128 + ((c*2) ^ ((i & 7) << 4))) = f2bf(o4[tc][r]);
            }
    }

    LGKMW();   // this wave's O writes drained; cross-wave covered by kc=0 barrier

    // ================= outproj: Y[128x512] = O_lds * Wob^T + bias =================
    float br[32];
    #pragma unroll
    for (int cf = 0; cf < 32; ++cf) br[cf] = bias[cf*16 + li];

    f32x4 y[32];
    #pragma unroll
    for (int cf = 0; cf < 32; ++cf) y[cf] = f32x4{0.f,0.f,0.f,0.f};

    for (int kc = 0; kc < 16; ++kc) {
        // stage Bs = Wob[:, kc*32..+32) (32KB), R6 slot-XOR
        #pragma unroll
        for (int p = 0; p < 4; ++p) {
            int co = p*128 + (tid >> 2);
            int cq = (tid & 3) ^ ((co >> 1) & 3);
            gload16(Wob + (size_t)co*512 + kc*32 + cq*8, SB + p*8192 + tid*16);
        }
        VMC(0); LGKMW();
        SBAR();            // Bs ready (kc=0: also all O writes visible)

        int i = wv*16 + li;
        bf16x8 af = *(const bf16x8*)(sm + (kc >> 1)*16384 + i*128 +
                                     (((kc & 1)*64 + lg*16) ^ ((li & 7) << 4)));
        __builtin_amdgcn_s_setprio(1);
        #pragma unroll
        for (int cf = 0; cf < 32; ++cf) {
            int co = cf*16 + li;
            bf16x8 bf = *(const bf16x8*)(SB + co*64 + ((lg << 4) ^ (((co >> 1) & 3) << 4)));
            y[cf] = __builtin_amdgcn_mfma_f32_16x16x32_bf16(af, bf, y[cf], 0, 0, 0);
        }
        __builtin_amdgcn_s_setprio(0);
        SBAR();            // Bs reads done before next stage
    }

    // epilogue: Y -> out (NHWC), rows = (nb*128 + i)*128 + w
    #pragma unroll
    for (int cf = 0; cf < 32; ++cf)
        #pragma unroll
        for (int r = 0; r < 4; ++r) {
            int i = wv*16 + lg*4 + r;
            int co = cf*16 + li;
            out[((size_t)(nb*128 + i)*128 + w)*512 + co] = y[cf][r] + br[cf];
        }
}

extern "C" void kernel_launch(void* const* d_in, const int* in_sizes, int n_in,
                              void* d_out, int out_size, void* d_ws, size_t ws_size,
                              hipStream_t stream){
    const float* x  = (const float*)d_in[0];
    const float* Wq = (const float*)d_in[1];
    const float* Wk = (const float*)d_in[2];
    const float* Wv = (const float*)d_in[3];
    const float* Wo = (const float*)d_in[4];
    const float* bo = (const float*)d_in[5];

    char* ws = (char*)d_ws;
    u16* Wcat = (u16*)ws;               // 1536*512 bf16
    u16* Wob  = Wcat + 1536*512;        // 512*512 bf16 ; weights end at 2097152 B

    int CN = 1024;
    while (CN > 128 && (size_t)2097152 + (size_t)CN*524288 > ws_size) CN >>= 1;
    u16* xb   = (u16*)(ws + 2097152);
    u16* QKV2 = xb + (size_t)CN*128*512;   // 3 planes [CN*128][512]
    int planesz = CN*128*512;

    hipFuncSetAttribute((const void*)&k_gemm4<6>,
                        hipFuncAttributeMaxDynamicSharedMemorySize, 131072);
    hipFuncSetAttribute((const void*)&k_fused,
                        hipFuncAttributeMaxDynamicSharedMemorySize, 163840);

    k_wconv<<<1024, 256, 0, stream>>>(Wq, Wk, Wv, Wo, Wcat, Wob);
    int nch = 1024 / CN;
    for (int ch = 0; ch < nch; ++ch) {
        int n0 = ch * CN;
        int nrow = (CN * 128) / 256;
        k_xconv<<<CN*32, 256, 0, stream>>>(x, xb, n0);
        k_gemm4<6><<<nrow*6, 512, 131072, stream>>>(xb, Wcat, QKV2, nrow, planesz);
        k_fused<<<CN, 512, 163840, stream>>>(QKV2, QKV2 + planesz, QKV2 + 2*(size_t)planesz,
                                             Wob, bo, (float*)d_out, n0, CN/8);
    }
}